// Round 6
// baseline (585.922 us; speedup 1.0000x reference)
//
#include <hip/hip_runtime.h>
#include <hip/hip_bf16.h>
#include <stdint.h>

// out[b,o,k] = sum_{h,m} W[o, h*64+m] * xl[b,h,k] * x0[b,m,k] + bias[o]
// B=256, M=H=64, K=128, OUT=256, C=4096.
// v6: out = sum_h xl[h,n] * (W_h @ x0), 32x32x16 MFMA, ALL-REGISTER W pipeline.
//  - grid (8,256) = 2048 single-wave blocks (64 thr). Wave owns o-tile
//    got=blockIdx.x (32 rows) x all 128 k x one b. No LDS, no barriers.
//  - W A-frags stream global->VGPR (4 x global_load_dwordx4 per h from the
//    pre-tiled bf16 Wb in d_ws), double-buffered (afA/afB), unroll-by-2.
//  - xl read as f32 scalars (L2), double-buffered (xlA/xlB).
//  - x0 B-frags h-invariant in registers (32 VGPR).
//  - h-loop start rotated by b (h0 = b & 63) to decorrelate L2 line access
//    across blocks sharing the same Wb rows.

typedef __attribute__((ext_vector_type(8)))  short short8;
typedef __attribute__((ext_vector_type(16))) float f32x16;

#define B_SZ   256
#define K_SZ   128
#define OUT_SZ 256
#define C_SZ   4096
#define NH     64

__device__ __forceinline__ uint32_t pack_bf16(float a, float b) {
    __hip_bfloat162 h2 = __float22bfloat162_rn(make_float2(a, b));
    union { __hip_bfloat162 h; uint32_t u; } v;
    v.h = h2;
    return v.u;
}

// ---- W f32 -> bf16 tiled for 32x32x16 A-frags (same layout as v4/v5) ----
// subtile s4 = got*256 + cb16 (512 shorts, lane-linear):
//   element (o = got*32 + (lane&31), c = cb16*16 + (lane>>5)*8 + j)
__global__ void convert_W_tiled(const float* __restrict__ W, short* __restrict__ Wb) {
    int t = blockIdx.x * blockDim.x + threadIdx.x;   // 0..131071
    int lane = t & 63;
    int sub  = t >> 6;          // 0..2047
    int cb16 = sub & 255;
    int got  = sub >> 8;        // 0..7
    int o = got * 32 + (lane & 31);
    int c = cb16 * 16 + (lane >> 5) * 8;
    const float* p = W + (size_t)o * C_SZ + c;
    float4 w0 = *(const float4*)p;
    float4 w1 = *(const float4*)(p + 4);
    union { short8 s; uint32_t u[4]; } cc;
    cc.u[0] = pack_bf16(w0.x, w0.y);
    cc.u[1] = pack_bf16(w0.z, w0.w);
    cc.u[2] = pack_bf16(w1.x, w1.y);
    cc.u[3] = pack_bf16(w1.z, w1.w);
    *(short8*)(Wb + (size_t)t * 8) = cc.s;
}

template<bool USE_WS>
__global__ __launch_bounds__(64, 3)
void cin_main(const float* __restrict__ x0, const float* __restrict__ xl,
              const float* __restrict__ Wf, const short* __restrict__ Wb,
              const float* __restrict__ bias, float* __restrict__ out) {
    const int b    = blockIdx.y;
    const int got  = blockIdx.x;        // o-tile 0..7
    const int lane = threadIdx.x;       // 0..63
    const int l31  = lane & 31;
    const int hi   = lane >> 5;

    // ---- x0 B-frags (h-invariant), 32x32x16 layout: 32 VGPRs ----
    // x0p[s][nt].j = x0[m = s*16 + hi*8 + j][n = nt*32 + l31]
    union { short8 s; uint32_t u[4]; } x0p[4][4];
    {
        const float* x0b = x0 + (size_t)b * (64 * K_SZ);
#pragma unroll
        for (int s = 0; s < 4; ++s)
#pragma unroll
            for (int nt = 0; nt < 4; ++nt)
#pragma unroll
                for (int t2 = 0; t2 < 4; ++t2) {
                    const int m0 = s * 16 + hi * 8 + 2 * t2;
                    const int cc = nt * 32 + l31;
                    x0p[s][nt].u[t2] = pack_bf16(x0b[m0 * K_SZ + cc],
                                                 x0b[(m0 + 1) * K_SZ + cc]);
                }
    }

    // ---- streaming sources ----
    const short* wsrc  = Wb + ((size_t)got * 256) * 512 + (size_t)lane * 8;
    const float* wfrow = Wf + (size_t)(got * 32 + l31) * C_SZ + hi * 8;
    const float* xlb   = xl + (size_t)b * (NH * K_SZ);
    const int h0 = b & (NH - 1);        // per-block h rotation

    auto LOAD_AF = [&](short8* dst, int hh) {
        if (USE_WS) {
            const short* s0 = wsrc + (size_t)(4 * hh) * 512;
#pragma unroll
            for (int sub = 0; sub < 4; ++sub)
                dst[sub] = *(const short8*)(s0 + sub * 512);
        } else {
#pragma unroll
            for (int sub = 0; sub < 4; ++sub) {
                const float* p = wfrow + hh * 64 + sub * 16;
                float4 w0 = *(const float4*)p;
                float4 w1 = *(const float4*)(p + 4);
                union { short8 s; uint32_t u[4]; } cc;
                cc.u[0] = pack_bf16(w0.x, w0.y);
                cc.u[1] = pack_bf16(w0.z, w0.w);
                cc.u[2] = pack_bf16(w1.x, w1.y);
                cc.u[3] = pack_bf16(w1.z, w1.w);
                dst[sub] = cc.s;
            }
        }
    };
    auto LOAD_XL = [&](float* dst, int hh) {
#pragma unroll
        for (int nt = 0; nt < 4; ++nt)
            dst[nt] = xlb[hh * K_SZ + nt * 32 + l31];
    };

    f32x16 acc[4];
#pragma unroll
    for (int nt = 0; nt < 4; ++nt)
#pragma unroll
        for (int r = 0; r < 16; ++r) acc[nt][r] = 0.f;
    f32x16 kz;
#pragma unroll
    for (int r = 0; r < 16; ++r) kz[r] = 0.f;

    short8 afA[4], afB[4];
    float  xlA[4], xlB[4];
    LOAD_AF(afA, h0);
    LOAD_XL(xlA, h0);
    LOAD_AF(afB, (h0 + 1) & (NH - 1));
    LOAD_XL(xlB, (h0 + 1) & (NH - 1));

#define COMPUTE(AF, XL)                                                          \
    do {                                                                         \
        _Pragma("unroll")                                                        \
        for (int nt = 0; nt < 4; ++nt) {                                         \
            f32x16 g = __builtin_amdgcn_mfma_f32_32x32x16_bf16(AF[0], x0p[0][nt].s, kz, 0, 0, 0); \
            g = __builtin_amdgcn_mfma_f32_32x32x16_bf16(AF[1], x0p[1][nt].s, g, 0, 0, 0); \
            g = __builtin_amdgcn_mfma_f32_32x32x16_bf16(AF[2], x0p[2][nt].s, g, 0, 0, 0); \
            g = __builtin_amdgcn_mfma_f32_32x32x16_bf16(AF[3], x0p[3][nt].s, g, 0, 0, 0); \
            _Pragma("unroll")                                                    \
            for (int r = 0; r < 16; ++r)                                         \
                acc[nt][r] += XL[nt] * g[r];                                     \
        }                                                                        \
    } while (0)

    for (int i = 0; i < NH; i += 2) {
        COMPUTE(afA, xlA);
        {   // prefetch h0+i+2 into the A set (wraps harmlessly at tail)
            const int hh = (h0 + i + 2) & (NH - 1);
            LOAD_AF(afA, hh);
            LOAD_XL(xlA, hh);
        }
        COMPUTE(afB, xlB);
        {   // prefetch h0+i+3 into the B set
            const int hh = (h0 + i + 3) & (NH - 1);
            LOAD_AF(afB, hh);
            LOAD_XL(xlB, hh);
        }
    }
#undef COMPUTE

    // ---- epilogue: bias + store ----
    // 32x32 C/D: col(k) = l31, row(o) = (r&3) + 8*(r>>2) + 4*hi   [m74/m101]
    float bv[16];
#pragma unroll
    for (int r = 0; r < 16; ++r)
        bv[r] = bias[got * 32 + (r & 3) + 8 * (r >> 2) + 4 * hi];

    float* outb = out + (size_t)b * (OUT_SZ * K_SZ);
#pragma unroll
    for (int nt = 0; nt < 4; ++nt) {
        const int kcol = nt * 32 + l31;
#pragma unroll
        for (int r = 0; r < 16; ++r) {
            const int orow = got * 32 + (r & 3) + 8 * (r >> 2) + 4 * hi;
            outb[orow * K_SZ + kcol] = acc[nt][r] + bv[r];
        }
    }
}

extern "C" void kernel_launch(void* const* d_in, const int* in_sizes, int n_in,
                              void* d_out, int out_size, void* d_ws, size_t ws_size,
                              hipStream_t stream) {
    const float* x0   = (const float*)d_in[0];
    const float* xl   = (const float*)d_in[1];
    // d_in[2] is the scalar k (=128) — fixed by the problem shape
    const float* W    = (const float*)d_in[3];
    const float* bias = (const float*)d_in[4];
    float* out = (float*)d_out;

    const size_t w_bytes = (size_t)OUT_SZ * C_SZ * sizeof(short);
    short* Wb = (short*)d_ws;

    if (ws_size >= w_bytes) {
        convert_W_tiled<<<dim3(512), dim3(256), 0, stream>>>(W, Wb);
        cin_main<true><<<dim3(8, B_SZ), dim3(64), 0, stream>>>(x0, xl, W, Wb, bias, out);
    } else {
        cin_main<false><<<dim3(8, B_SZ), dim3(64), 0, stream>>>(x0, xl, W, Wb, bias, out);
    }
}

// Round 7
// 81.711 us; speedup vs baseline: 7.1706x; 7.1706x over previous
//
#include <hip/hip_runtime.h>
#include <hip/hip_bf16.h>
#include <stdint.h>

// out[b,o,k] = sum_{h,m} W[o, h*64+m] * xl[b,h,k] * x0[b,m,k] + bias[o]
// B=256, M=H=64, K=128, OUT=256, C=4096.
// v7: v5 skeleton (private per-wave W staging, counted vmcnt, no in-loop
// barriers) + software-pipelined xl-scale tail (parity-buffered gE/gO, lag-2)
// so the 64-fma tail overlaps the MFMA chains + 2-buf ring (48 KB LDS ->
// 3 blocks/CU) + setprio around the MFMA region.

typedef __attribute__((ext_vector_type(8)))  short short8;
typedef __attribute__((ext_vector_type(16))) float f32x16;

#define B_SZ   256
#define K_SZ   128
#define OUT_SZ 256
#define C_SZ   4096
#define NH     64

__device__ __forceinline__ uint32_t pack_bf16(float a, float b) {
    __hip_bfloat162 h2 = __float22bfloat162_rn(make_float2(a, b));
    union { __hip_bfloat162 h; uint32_t u; } v;
    v.h = h2;
    return v.u;
}

__device__ __forceinline__ float bf2f(short s) {
    union { uint32_t u; float f; } v;
    v.u = ((uint32_t)(uint16_t)s) << 16;
    return v.f;
}

__device__ __forceinline__ void load_lds_16(const void* g, void* l) {
    __builtin_amdgcn_global_load_lds(
        (const __attribute__((address_space(1))) unsigned int*)g,
        (__attribute__((address_space(3))) unsigned int*)l,
        16, 0, 0);
}

// ---- W f32 -> bf16 tiled for 32x32x16 A-frags (same layout as v4/v5) ----
// subtile = got*256 + cb16 (512 shorts, lane-linear):
//   element (o = got*32 + (lane&31), c = cb16*16 + (lane>>5)*8 + j)
__global__ void convert_W_tiled(const float* __restrict__ W, short* __restrict__ Wb) {
    int t = blockIdx.x * blockDim.x + threadIdx.x;   // 0..131071
    int lane = t & 63;
    int sub  = t >> 6;          // 0..2047
    int cb16 = sub & 255;
    int got  = sub >> 8;        // 0..7
    int o = got * 32 + (lane & 31);
    int c = cb16 * 16 + (lane >> 5) * 8;
    const float* p = W + (size_t)o * C_SZ + c;
    float4 w0 = *(const float4*)p;
    float4 w1 = *(const float4*)(p + 4);
    union { short8 s; uint32_t u[4]; } cc;
    cc.u[0] = pack_bf16(w0.x, w0.y);
    cc.u[1] = pack_bf16(w0.z, w0.w);
    cc.u[2] = pack_bf16(w1.x, w1.y);
    cc.u[3] = pack_bf16(w1.z, w1.w);
    *(short8*)(Wb + (size_t)t * 8) = cc.s;
}

template<bool USE_WS>
__global__ __launch_bounds__(256, 2)
void cin_main(const float* __restrict__ x0, const float* __restrict__ xl,
              const float* __restrict__ Wf, const short* __restrict__ Wb,
              const float* __restrict__ bias, float* __restrict__ out) {
    __shared__ short Wlds[4 * 2 * 2048];   // [wave][buf 0..1][2048] = 32 KB
    __shared__ short xls[NH * K_SZ];       // 16 KB bf16 [h][k]

    const int b     = blockIdx.y;
    const int ohalf = blockIdx.x;
    const int tid   = threadIdx.x;
    const int lane  = tid & 63;
    const int wave  = tid >> 6;            // 0..3
    const int got   = ohalf * 4 + wave;    // o-tile 0..7
    const int l31   = lane & 31;
    const int hi    = lane >> 5;

    // ---- stage xl as bf16 into LDS (256 thr x 32 elems) ----
    {
        const float4* src = (const float4*)(xl + (size_t)b * (NH * K_SZ));
        uint32_t* dst = (uint32_t*)&xls[tid * 32];
#pragma unroll
        for (int i = 0; i < 8; ++i) {
            float4 v = src[tid * 8 + i];
            dst[2 * i]     = pack_bf16(v.x, v.y);
            dst[2 * i + 1] = pack_bf16(v.z, v.w);
        }
    }

    // ---- x0 B-frags (h-invariant), 32x32x16 layout: 64 VGPRs ----
    // x0p[s][nt].j = x0[m = s*16 + hi*8 + j][n = nt*32 + l31]
    union { short8 s; uint32_t u[4]; } x0p[4][4];
    {
        const float* x0b = x0 + (size_t)b * (64 * K_SZ);
#pragma unroll
        for (int s = 0; s < 4; ++s)
#pragma unroll
            for (int nt = 0; nt < 4; ++nt)
#pragma unroll
                for (int t2 = 0; t2 < 4; ++t2) {
                    const int m0 = s * 16 + hi * 8 + 2 * t2;
                    const int cc = nt * 32 + l31;
                    x0p[s][nt].u[t2] = pack_bf16(x0b[m0 * K_SZ + cc],
                                                 x0b[(m0 + 1) * K_SZ + cc]);
                }
    }

    // ---- per-wave-private W staging (2-buf ring) ----
    const short* wsrc  = Wb + ((size_t)got * 256) * 512 + lane * 8;
    const float* wfrow = Wf + (size_t)(got * 32 + l31) * C_SZ + hi * 8;
    short* wl = Wlds + wave * (2 * 2048);

    auto stage = [&](int buf, int h) {
        if (USE_WS) {
            const short* s0 = wsrc + (size_t)(4 * h) * 512;
            short* d = wl + buf * 2048;
#pragma unroll
            for (int sub = 0; sub < 4; ++sub)
                load_lds_16(s0 + sub * 512, d + sub * 512);
        } else {
#pragma unroll
            for (int sub = 0; sub < 4; ++sub) {
                const float* p = wfrow + h * 64 + sub * 16;
                float4 w0 = *(const float4*)p;
                float4 w1 = *(const float4*)(p + 4);
                union { short8 s; uint32_t u[4]; } cc;
                cc.u[0] = pack_bf16(w0.x, w0.y);
                cc.u[1] = pack_bf16(w0.z, w0.w);
                cc.u[2] = pack_bf16(w1.x, w1.y);
                cc.u[3] = pack_bf16(w1.z, w1.w);
                *(short8*)(wl + buf * 2048 + sub * 512 + lane * 8) = cc.s;
            }
        }
    };

    f32x16 acc[4];
#pragma unroll
    for (int nt = 0; nt < 4; ++nt)
#pragma unroll
        for (int r = 0; r < 16; ++r) acc[nt][r] = 0.f;
    f32x16 kz;
#pragma unroll
    for (int r = 0; r < 16; ++r) kz[r] = 0.f;

    // prologue: stage h=0 (buf0), h=1 (buf1); one barrier for xls only
    stage(0, 0);
    stage(1, 1);
    __syncthreads();

    // pipelined-tail state: gE/gO carry chain results with lag 2 (parity)
    f32x16 gE = kz, gO = kz;
    float px2 = 0.f, px3 = 0.f;

#define CHAIN(G, NT)                                                                   \
    do {                                                                               \
        G = __builtin_amdgcn_mfma_f32_32x32x16_bf16(af0, x0p[0][NT].s, kz, 0, 0, 0);   \
        G = __builtin_amdgcn_mfma_f32_32x32x16_bf16(af1, x0p[1][NT].s, G, 0, 0, 0);    \
        G = __builtin_amdgcn_mfma_f32_32x32x16_bf16(af2, x0p[2][NT].s, G, 0, 0, 0);    \
        G = __builtin_amdgcn_mfma_f32_32x32x16_bf16(af3, x0p[3][NT].s, G, 0, 0, 0);    \
    } while (0)

#define TAIL(ACC_I, PX, G)                                                             \
    do {                                                                               \
        _Pragma("unroll")                                                              \
        for (int r = 0; r < 16; ++r) acc[ACC_I][r] += (PX) * G[r];                     \
    } while (0)

    for (int h = 0; h < NH; ++h) {
        // wait for this h's 4 staged loads (h+1's 4 remain in flight)
        if (USE_WS) asm volatile("s_waitcnt vmcnt(4)" ::: "memory");

        const short* wb2 = wl + (h & 1) * 2048 + lane * 8;
        const short8 af0 = *(const short8*)(wb2);
        const short8 af1 = *(const short8*)(wb2 + 512);
        const short8 af2 = *(const short8*)(wb2 + 1024);
        const short8 af3 = *(const short8*)(wb2 + 1536);

        const float xlv0 = bf2f(xls[h * K_SZ + 0 * 32 + l31]);
        const float xlv1 = bf2f(xls[h * K_SZ + 1 * 32 + l31]);
        const float xlv2 = bf2f(xls[h * K_SZ + 2 * 32 + l31]);
        const float xlv3 = bf2f(xls[h * K_SZ + 3 * 32 + l31]);

        __builtin_amdgcn_s_setprio(1);
        // site 0: flush prev-h nt2's g (gE), then chain nt0 -> gE
        TAIL(2, px2, gE);
        CHAIN(gE, 0);
        // site 1: flush prev-h nt3's g (gO), then chain nt1 -> gO
        TAIL(3, px3, gO);
        CHAIN(gO, 1);
        // site 2: flush this-h nt0's g (gE), then chain nt2 -> gE
        TAIL(0, xlv0, gE);
        CHAIN(gE, 2);
        // site 3: flush this-h nt1's g (gO), then chain nt3 -> gO
        TAIL(1, xlv1, gO);
        CHAIN(gO, 3);
        __builtin_amdgcn_s_setprio(0);

        px2 = xlv2;
        px3 = xlv3;

        // ds_reads of this h are complete before we overwrite buf (h&1)
        asm volatile("s_waitcnt lgkmcnt(0)" ::: "memory");
        stage(h & 1, (h + 2) & (NH - 1));
    }

    // flush the last two pending chains (h=63: nt2 -> acc[2], nt3 -> acc[3])
    TAIL(2, px2, gE);
    TAIL(3, px3, gO);
#undef CHAIN
#undef TAIL

    // ---- epilogue: bias + store ----
    // 32x32 C/D: col(k) = l31, row(o) = (r&3) + 8*(r>>2) + 4*hi   [m74/m101]
    float bv[16];
#pragma unroll
    for (int r = 0; r < 16; ++r)
        bv[r] = bias[got * 32 + (r & 3) + 8 * (r >> 2) + 4 * hi];

    float* outb = out + (size_t)b * (OUT_SZ * K_SZ);
#pragma unroll
    for (int nt = 0; nt < 4; ++nt) {
        const int kcol = nt * 32 + l31;
#pragma unroll
        for (int r = 0; r < 16; ++r) {
            const int orow = got * 32 + (r & 3) + 8 * (r >> 2) + 4 * hi;
            outb[orow * K_SZ + kcol] = acc[nt][r] + bv[r];
        }
    }
}

extern "C" void kernel_launch(void* const* d_in, const int* in_sizes, int n_in,
                              void* d_out, int out_size, void* d_ws, size_t ws_size,
                              hipStream_t stream) {
    const float* x0   = (const float*)d_in[0];
    const float* xl   = (const float*)d_in[1];
    // d_in[2] is the scalar k (=128) — fixed by the problem shape
    const float* W    = (const float*)d_in[3];
    const float* bias = (const float*)d_in[4];
    float* out = (float*)d_out;

    const size_t w_bytes = (size_t)OUT_SZ * C_SZ * sizeof(short);
    short* Wb = (short*)d_ws;

    if (ws_size >= w_bytes) {
        convert_W_tiled<<<dim3(512), dim3(256), 0, stream>>>(W, Wb);
        cin_main<true><<<dim3(2, B_SZ), dim3(256), 0, stream>>>(x0, xl, W, Wb, bias, out);
    } else {
        cin_main<false><<<dim3(2, B_SZ), dim3(256), 0, stream>>>(x0, xl, W, Wb, bias, out);
    }
}